// Round 1
// baseline (1197.729 us; speedup 1.0000x reference)
//
#include <hip/hip_runtime.h>

#define SEQ      2048
#define DIMS     2048
#define PAD      512
#define NTHREADS 256

// One block per (b, d) row. Direct causal FIR in fp32:
//   y[t] = x[t] + bias[d] + sum_{s<=t} k[s] * x[t-s]
// Each thread computes 8 consecutive outputs with a 16-register sliding
// x-window; k taps are wave-uniform LDS broadcasts. Per-wave causal bound.
__global__ __launch_bounds__(NTHREADS, 8)
void hyena_conv_kernel(const float* __restrict__ x,
                       const float* __restrict__ kern,
                       const float* __restrict__ bias,
                       float* __restrict__ out)
{
    __shared__ float xs[PAD + SEQ];   // xs[PAD + i] = x[i]; xs[0..PAD) = 0
    __shared__ float ks[SEQ];

    const int row = blockIdx.x;                 // row = b * DIMS + d
    const int d   = row & (DIMS - 1);
    const int tid = threadIdx.x;
    const long long base = (long long)row * SEQ;

    // ---- stage x row and kernel row into LDS (coalesced float4) ----
    {
        const int i0 = tid * 8;                 // 256 threads * 8 = 2048
        *(float4*)&xs[PAD + i0]     = *(const float4*)&x[base + i0];
        *(float4*)&xs[PAD + i0 + 4] = *(const float4*)&x[base + i0 + 4];
        *(float4*)&ks[i0]           = *(const float4*)&kern[base + i0];
        *(float4*)&ks[i0 + 4]       = *(const float4*)&kern[base + i0 + 4];
        if (tid < PAD / 8) {                    // zero the negative-index pad
            *(float4*)&xs[tid * 8]     = make_float4(0.f, 0.f, 0.f, 0.f);
            *(float4*)&xs[tid * 8 + 4] = make_float4(0.f, 0.f, 0.f, 0.f);
        }
    }
    __syncthreads();

    // Rotate wave->t-range assignment by blockIdx so long chunks (wv=3)
    // spread across SIMDs instead of always hitting the same one.
    const int wv  = ((tid >> 6) + blockIdx.x) & 3;   // virtual wave id 0..3
    const int ln  = tid & 63;
    const int t0  = wv * 512 + ln * 8;               // this thread's 8 outputs
    const int nch = 64 * (wv + 1);                   // s-chunks: s < 512*(wv+1)

    float acc[8];
#pragma unroll
    for (int i = 0; i < 8; ++i) acc[i] = 0.f;

    // xw[z] = x[t0 - s8 - 8 + z], z in [0,16). Maintained across chunks.
    float xw[16];
    {
        float4 a = *(float4*)&xs[PAD + t0];
        float4 b = *(float4*)&xs[PAD + t0 + 4];
        xw[8] = a.x; xw[9] = a.y; xw[10] = a.z; xw[11] = a.w;
        xw[12] = b.x; xw[13] = b.y; xw[14] = b.z; xw[15] = b.w;
    }

    for (int c = 0; c < nch; ++c) {
        const int s8 = c * 8;
        // load 8 new window values: xw[0..7] = x[t0 - s8 - 8 .. t0 - s8 - 1]
        {
            float4 a = *(float4*)&xs[PAD + t0 - s8 - 8];
            float4 b = *(float4*)&xs[PAD + t0 - s8 - 4];
            xw[0] = a.x; xw[1] = a.y; xw[2] = a.z; xw[3] = a.w;
            xw[4] = b.x; xw[5] = b.y; xw[6] = b.z; xw[7] = b.w;
        }
        // 8 kernel taps (wave-uniform address -> broadcast, conflict-free)
        float kk[8];
        {
            float4 a = *(float4*)&ks[s8];
            float4 b = *(float4*)&ks[s8 + 4];
            kk[0] = a.x; kk[1] = a.y; kk[2] = a.z; kk[3] = a.w;
            kk[4] = b.x; kk[5] = b.y; kk[6] = b.z; kk[7] = b.w;
        }
        // 64 FMAs: acc[i] += k[s8+j] * x[t0 + i - (s8+j)]
        // x index t-s may be negative for s>t -> hits the zero pad. Correct.
#pragma unroll
        for (int j = 0; j < 8; ++j) {
#pragma unroll
            for (int i = 0; i < 8; ++i) {
                acc[i] += kk[j] * xw[8 + i - j];
            }
        }
        // slide window down by 8 for next chunk
#pragma unroll
        for (int z = 0; z < 8; ++z) xw[8 + z] = xw[z];
    }

    // ---- epilogue: y = conv + x + bias ----
    {
        const float bv = bias[d];
        float4 o0, o1;
        o0.x = acc[0] + xs[PAD + t0 + 0] + bv;
        o0.y = acc[1] + xs[PAD + t0 + 1] + bv;
        o0.z = acc[2] + xs[PAD + t0 + 2] + bv;
        o0.w = acc[3] + xs[PAD + t0 + 3] + bv;
        o1.x = acc[4] + xs[PAD + t0 + 4] + bv;
        o1.y = acc[5] + xs[PAD + t0 + 5] + bv;
        o1.z = acc[6] + xs[PAD + t0 + 6] + bv;
        o1.w = acc[7] + xs[PAD + t0 + 7] + bv;
        *(float4*)&out[base + t0]     = o0;
        *(float4*)&out[base + t0 + 4] = o1;
    }
}

extern "C" void kernel_launch(void* const* d_in, const int* in_sizes, int n_in,
                              void* d_out, int out_size, void* d_ws, size_t ws_size,
                              hipStream_t stream) {
    const float* x    = (const float*)d_in[0];   // (4, 2048, 2048) f32
    const float* kern = (const float*)d_in[1];   // (4, 2048, 2048) f32
    const float* bias = (const float*)d_in[2];   // (2048,) f32
    float* out = (float*)d_out;                  // (4, 2048, 2048) f32

    const int n_rows = 4 * DIMS;                 // 8192
    hipLaunchKernelGGL(hyena_conv_kernel, dim3(n_rows), dim3(NTHREADS), 0, stream,
                       x, kern, bias, out);
}

// Round 2
// 69.544 us; speedup vs baseline: 17.2225x; 17.2225x over previous
//
#include <hip/hip_runtime.h>

typedef __attribute__((ext_vector_type(8)))  short short8;
typedef __attribute__((ext_vector_type(16))) float f32x16;

#define SEQ    2048
#define XPITCH 20                 // u32 per xlds row (40 bf16 = 80B, odd multiple of 16B)
#define XROWS  96                 // rows 0..31 zero pad (negative blocks), 32..95 = x blocks 0..63
#define XSZ    (XROWS * XPITCH)   // 1920 u32
#define KSZ    1044               // u32 per krev buffer (covers index 0..1043)
#define WSZ    (XSZ + 2 * KSZ)    // 4008 u32 per wave-row

__device__ inline unsigned int pack_bf16_2(float lo, float hi) {
    unsigned int ul = __float_as_uint(lo);
    unsigned int uh = __float_as_uint(hi);
    ul = (ul + 0x7fffu + ((ul >> 16) & 1u)) >> 16;   // round-to-nearest-even
    uh = (uh + 0x7fffu + ((uh >> 16) & 1u)) >> 16;
    return (ul & 0xffffu) | (uh << 16);
}

#define MFMA(A, B, C) __builtin_amdgcn_mfma_f32_32x32x16_bf16( \
    __builtin_bit_cast(short8, A), __builtin_bit_cast(short8, B), C, 0, 0, 0)

// One wave per (b,d) row. Y(64x32) = sum_r shift_r(X) * T_r^T via 32x32x16 bf16 MFMA.
__global__ __launch_bounds__(256, 2)
void hyena_mfma(const float* __restrict__ x, const float* __restrict__ kern,
                const float* __restrict__ bias, float* __restrict__ out)
{
    __shared__ __align__(16) unsigned int lds[4 * WSZ];   // 64128 B

    const int tid = threadIdx.x;
    const int wid = tid >> 6;
    const int l   = tid & 63;
    const int n   = l & 31;       // MFMA row (A) / col (B/D)
    const int hi  = l >> 5;       // k-group half
    const int row = blockIdx.x * 4 + wid;          // (b*2048 + d)
    const size_t rb = (size_t)row * SEQ;

    unsigned int* xld  = lds + wid * WSZ;          // [96][20] u32: bf16 x blocks, rows padded
    unsigned int* bufA = xld + XSZ;                // krev pairs, even alignment
    unsigned int* bufB = bufA + KSZ;               // krev shifted by one element

    // ---- stage x row as bf16 into xld rows 32..95 ----
    #pragma unroll
    for (int it = 0; it < 16; ++it) {
        const int e = it * 128 + 2 * l;
        float2 v = *(const float2*)&x[rb + e];
        const int R = 32 + (e >> 5);
        xld[R * XPITCH + ((e & 31) >> 1)] = pack_bf16_2(v.x, v.y);
    }
    // zero pad rows 0..31 (blocks with negative index)
    #pragma unroll
    for (int it = 0; it < 10; ++it) xld[it * 64 + l] = 0u;

    // ---- stage krev: krev[j] = k[2047-j], zero for j >= 2048 ----
    // bufA[j>>1] = (krev[j] lo, krev[j+1] hi)
    #pragma unroll
    for (int it = 0; it < 16; ++it) {
        const int j = it * 128 + 2 * l;
        float2 v = *(const float2*)&kern[rb + (2046 - j)];  // (k[2046-j], k[2047-j])
        bufA[j >> 1] = pack_bf16_2(v.y, v.x);               // (krev[j], krev[j+1])
    }
    if (l < 20) bufA[1024 + l] = 0u;                        // krev tail zeros
    __syncthreads();

    // bufB[m] = (krev[2m+1], krev[2m+2])
    #pragma unroll
    for (int it = 0; it < 17; ++it) {
        const int m = it * 64 + l;
        if (m < 1040) {
            unsigned int a = bufA[m], b = bufA[m + 1];
            bufB[m] = (a >> 16) | (b << 16);
        }
    }
    __syncthreads();

    // ---- main loop: r = 0..31; tiles m=0 (T_r), m=1 (T_r and T_{r+32}) ----
    // A-frag(o,s): lane element i' = 16s + 8*hi + v  ->  x[32*(o+n) + i']
    // B-frag(r,s): value v = k[32r + n - i']  = krev[base0 - 64r(/2 in u32) ...]
    int iA = (32 + n) * XPITCH + 4 * hi;     // u32 index of A(-0, s0)
    const int base0 = 2047 - n + 8 * hi;     // krev element index at r=0,s=0,v=0
    const unsigned int* kb;
    int iK;
    if (base0 & 1) { kb = bufB; iK = (base0 - 1) >> 1; }
    else           { kb = bufA; iK = base0 >> 1; }

    f32x16 acc0 = {}, acc1a = {}, acc1b = {};

    #pragma unroll 4
    for (int r = 0; r < 32; ++r) {
        const uint4 a00 = *(const uint4*)(xld + iA);                    // A(-r,  s0)
        const uint4 a01 = *(const uint4*)(xld + iA + 8);                // A(-r,  s1)
        const uint4 a10 = *(const uint4*)(xld + iA + 32 * XPITCH);      // A(32-r,s0)
        const uint4 a11 = *(const uint4*)(xld + iA + 32 * XPITCH + 8);  // A(32-r,s1)
        uint4 b00, b01, b10, b11;   // T_r s0/s1, T_{r+32} s0/s1 (4 consecutive u32 each)
        b00.x = kb[iK];       b00.y = kb[iK + 1];   b00.z = kb[iK + 2];   b00.w = kb[iK + 3];
        b01.x = kb[iK + 8];   b01.y = kb[iK + 9];   b01.z = kb[iK + 10];  b01.w = kb[iK + 11];
        b10.x = kb[iK - 512]; b10.y = kb[iK - 511]; b10.z = kb[iK - 510]; b10.w = kb[iK - 509];
        b11.x = kb[iK - 504]; b11.y = kb[iK - 503]; b11.z = kb[iK - 502]; b11.w = kb[iK - 501];

        acc0  = MFMA(a00, b00, acc0);    // m=0 += X(-r)  * T_r^T
        acc0  = MFMA(a01, b01, acc0);
        acc1a = MFMA(a10, b00, acc1a);   // m=1 += X(32-r)* T_r^T
        acc1a = MFMA(a11, b01, acc1a);
        acc1b = MFMA(a00, b10, acc1b);   // m=1 += X(-r)  * T_{r+32}^T
        acc1b = MFMA(a01, b11, acc1b);

        iA -= XPITCH;
        iK -= 16;
    }

    // ---- epilogue: y[32p + n] = acc + x + bias ----
    const float bv = bias[row & 2047];
    #pragma unroll
    for (int mt = 0; mt < 2; ++mt) {
        #pragma unroll
        for (int t = 0; t < 16; ++t) {
            const int rloc = (t & 3) + 8 * (t >> 2) + 4 * hi;  // verified 32x32 C/D row map
            const int p = mt * 32 + rloc;
            const unsigned int w = xld[(32 + p) * XPITCH + (n >> 1)];
            const float xr = __uint_as_float((n & 1) ? (w & 0xffff0000u) : (w << 16));
            const float a = mt ? (acc1a[t] + acc1b[t]) : acc0[t];
            out[rb + (size_t)p * 32 + n] = a + xr + bv;
        }
    }
}

extern "C" void kernel_launch(void* const* d_in, const int* in_sizes, int n_in,
                              void* d_out, int out_size, void* d_ws, size_t ws_size,
                              hipStream_t stream) {
    const float* x    = (const float*)d_in[0];   // (4, 2048, 2048) f32
    const float* kern = (const float*)d_in[1];   // (4, 2048, 2048) f32
    const float* bias = (const float*)d_in[2];   // (2048,) f32
    float* out = (float*)d_out;                  // (4, 2048, 2048) f32

    hipLaunchKernelGGL(hyena_mfma, dim3(2048), dim3(256), 0, stream,
                       x, kern, bias, out);
}